// Round 5
// baseline (295.862 us; speedup 1.0000x reference)
//
#include <hip/hip_runtime.h>

typedef __attribute__((ext_vector_type(8))) short short8;
typedef __attribute__((ext_vector_type(4))) float floatx4;

#define CEMB 1024
#define NHEAD 16
#define HD 64
#define BATCH 4
#define SEQ 2048

// raw barrier: LDS-visibility only, no vmcnt drain (keeps register prefetch in flight)
#define BARRIER() asm volatile("s_waitcnt lgkmcnt(0)\n\ts_barrier" ::: "memory")

__device__ __forceinline__ unsigned short f2bf(float f) {
    union { float f; unsigned int i; } x; x.f = f;
    unsigned int r = x.i + 0x7FFFu + ((x.i >> 16) & 1u);
    return (unsigned short)(r >> 16);
}
// truncating bf16 pack of two floats (low = a, high = b)
__device__ __forceinline__ unsigned int packbf_trunc(float a, float b) {
    union { float f; unsigned int u; } x, y; x.f = a; y.f = b;
    return (x.u >> 16) | (y.u & 0xFFFF0000u);
}

#define GLD16(gp, lp) \
    __builtin_amdgcn_global_load_lds((const __attribute__((address_space(1))) void*)(gp), \
                                     (__attribute__((address_space(3))) void*)(lp), 16, 0, 0)

__global__ void cast_x(const float* __restrict__ src, unsigned short* __restrict__ dst, int n4) {
    int i = blockIdx.x * blockDim.x + threadIdx.x;
    if (i < n4) {
        float4 v = ((const float4*)src)[i];
        ushort4 o;
        o.x = f2bf(v.x); o.y = f2bf(v.y); o.z = f2bf(v.z); o.w = f2bf(v.w);
        ((ushort4*)dst)[i] = o;
    }
}

__global__ void cast_w(const float* __restrict__ w0, const float* __restrict__ w1,
                       const float* __restrict__ w2, const float* __restrict__ w3,
                       unsigned short* __restrict__ o0, unsigned short* __restrict__ o1,
                       unsigned short* __restrict__ o2, unsigned short* __restrict__ o3) {
    int which = blockIdx.y;
    const float* src = which == 0 ? w0 : which == 1 ? w1 : which == 2 ? w2 : w3;
    unsigned short* dst = which == 0 ? o0 : which == 1 ? o1 : which == 2 ? o2 : o3;
    // fold 1/sqrt(hd) AND log2(e) into Wq so attention can use raw v_exp (exp2)
    float scale = (which == 0) ? 0.125f * 1.44269504088896f : 1.0f;
    int i = blockIdx.x * blockDim.x + threadIdx.x;
    float4 v = ((const float4*)src)[i];
    ushort4 o;
    o.x = f2bf(v.x * scale); o.y = f2bf(v.y * scale);
    o.z = f2bf(v.z * scale); o.w = f2bf(v.w * scale);
    ((ushort4*)dst)[i] = o;
}

// ============================================================================
// GEMM, 128x256 tile, BK=64, 8 waves (2M x 4N), double-buffered LDS 96 KiB.
// (unchanged from round 4 -- frozen so next round's counters attribute cleanly)
// ============================================================================

#define MFMA __builtin_amdgcn_mfma_f32_16x16x32_bf16

// one phase: 12 ds_read_b128 + 16 MFMA (no barriers — compiler inserts lgkm waits)
#define PH(Ab, Bb, mh, nh) do {                                                 \
    short8 af[4][2], bfr[2][2];                                                 \
    _Pragma("unroll")                                                           \
    for (int mm = 0; mm < 4; ++mm) {                                            \
        af[mm][0] = *(const short8*)((Ab) + aOffR + (mh)*4096 + mm*1024 + ck0); \
        af[mm][1] = *(const short8*)((Ab) + aOffR + (mh)*4096 + mm*1024 + ck1); \
    }                                                                           \
    _Pragma("unroll")                                                           \
    for (int nn = 0; nn < 2; ++nn) {                                            \
        bfr[nn][0] = *(const short8*)((Bb) + bOffR + (nh)*2048 + nn*1024 + ck0);\
        bfr[nn][1] = *(const short8*)((Bb) + bOffR + (nh)*2048 + nn*1024 + ck1);\
    }                                                                           \
    __builtin_amdgcn_s_setprio(1);                                              \
    _Pragma("unroll")                                                           \
    for (int mm = 0; mm < 4; ++mm)                                              \
        _Pragma("unroll")                                                       \
        for (int nn = 0; nn < 2; ++nn) {                                        \
            acc[(mh)*4+mm][(nh)*2+nn] = MFMA(af[mm][0], bfr[nn][0],             \
                                             acc[(mh)*4+mm][(nh)*2+nn], 0,0,0); \
            acc[(mh)*4+mm][(nh)*2+nn] = MFMA(af[mm][1], bfr[nn][1],             \
                                             acc[(mh)*4+mm][(nh)*2+nn], 0,0,0); \
        }                                                                       \
    __builtin_amdgcn_s_setprio(0);                                              \
    __builtin_amdgcn_sched_barrier(0);                                          \
} while (0)

// stage one K-tile: A 128x64 (2 loads) + B 256x64 (4 loads)
#define STAGE(Ab, Bb, k0) do {                                                  \
    GLD16(aS + (k0),             (Ab) + aLA);                                   \
    GLD16(aS + (k0) +  8 * CEMB, (Ab) + aLA + 512);                             \
    GLD16(bS + (k0),             (Bb) + aLB);                                   \
    GLD16(bS + (k0) +  8 * CEMB, (Bb) + aLB + 512);                             \
    GLD16(bS + (k0) + 16 * CEMB, (Bb) + aLB + 1024);                            \
    GLD16(bS + (k0) + 24 * CEMB, (Bb) + aLB + 1536);                            \
} while (0)

// last phase (quadrant 0,1): reads, lgkm drain, barrier (buffer release),
// stage t+2 into the SAME buffer, then MFMAs on the already-fetched registers.
#define PH4(Ab, Bb, t, do_stage) do {                                           \
    short8 af[4][2], bfr[2][2];                                                 \
    _Pragma("unroll")                                                           \
    for (int mm = 0; mm < 4; ++mm) {                                            \
        af[mm][0] = *(const short8*)((Ab) + aOffR + mm*1024 + ck0);             \
        af[mm][1] = *(const short8*)((Ab) + aOffR + mm*1024 + ck1);             \
    }                                                                           \
    _Pragma("unroll")                                                           \
    for (int nn = 0; nn < 2; ++nn) {                                            \
        bfr[nn][0] = *(const short8*)((Bb) + bOffR + 2048 + nn*1024 + ck0);     \
        bfr[nn][1] = *(const short8*)((Bb) + bOffR + 2048 + nn*1024 + ck1);     \
    }                                                                           \
    asm volatile("s_waitcnt lgkmcnt(0)\n\ts_barrier" ::: "memory");             \
    __builtin_amdgcn_sched_barrier(0);                                          \
    if (do_stage) STAGE(Ab, Bb, ((t) + 2) * 64);                                \
    __builtin_amdgcn_s_setprio(1);                                              \
    _Pragma("unroll")                                                           \
    for (int mm = 0; mm < 4; ++mm)                                              \
        _Pragma("unroll")                                                       \
        for (int nn = 0; nn < 2; ++nn) {                                        \
            acc[mm][2+nn] = MFMA(af[mm][0], bfr[nn][0], acc[mm][2+nn], 0,0,0);  \
            acc[mm][2+nn] = MFMA(af[mm][1], bfr[nn][1], acc[mm][2+nn], 0,0,0);  \
        }                                                                       \
    __builtin_amdgcn_s_setprio(0);                                              \
    __builtin_amdgcn_sched_barrier(0);                                          \
} while (0)

// tile top: wait tile t resident (stage(t+1)'s 6 loads may stay in flight)
#define TILE(t, drain, do_stage) do {                                           \
    unsigned short* Ab = &As[(t) & 1][0];                                       \
    unsigned short* Bb = &Bs[(t) & 1][0];                                       \
    if (drain) { asm volatile("s_waitcnt vmcnt(0)" ::: "memory"); }             \
    else       { asm volatile("s_waitcnt vmcnt(6)" ::: "memory"); }             \
    asm volatile("s_barrier" ::: "memory");                                     \
    PH(Ab, Bb, 0, 0);                                                           \
    PH4(Ab, Bb, t, do_stage);                                                   \
} while (0)

__launch_bounds__(512, 2)
__global__ void gemm_128(const unsigned short* __restrict__ A,
                         const unsigned short* __restrict__ W,
                         void* __restrict__ O0, void* __restrict__ O1,
                         void* __restrict__ O2, int mode, int ntn) {
    __shared__ unsigned short As[2][8192];    // 2 x 128 rows x 64 cols bf16
    __shared__ unsigned short Bs[2][16384];   // 2 x 256 rows x 64 cols bf16

    // XCD-aware bijective swizzle (nwg % 8 == 0) + 8m x 4n supertile walk
    int nwg = gridDim.x;
    int bid = blockIdx.x;
    int wg = (bid & 7) * (nwg >> 3) + (bid >> 3);
    int cpr = ntn >> 2;                 // chunks per 8-row m-band
    int c = wg >> 5, r = wg & 31;
    int cm = c / cpr, cn = c - cm * cpr;
    int mt = cm * 8 + (r >> 2);
    int nt = cn * 4 + (r & 3);
    int m0 = mt * 128, n0 = nt * 256;

    int tid = threadIdx.x;
    int wave = tid >> 6, lane = tid & 63;
    int l16 = lane & 15, quad = lane >> 4;
    int wm = wave >> 2, wn = wave & 3;

    // staging: source col pre-swizzled: LDS slot c of row r holds chunk c^(r&7)
    int srow = lane >> 3;                       // 0..7
    int scol = ((lane & 7) ^ srow) * 8;
    const unsigned short* aS = A + (size_t)(m0 + wave * 16 + srow) * CEMB + scol;
    const unsigned short* bS = W + (size_t)(n0 + wave * 32 + srow) * CEMB + scol;
    int aLA = wave * 1024;                      // wave-uniform LDS slab offset
    int aLB = wave * 2048;

    // fragment-read addressing (row&7 == l16&7 for all frag rows)
    int aOffR = (wm * 64 + l16) * 64;
    int bOffR = (wn * 64 + l16) * 64;
    int ck0 = (quad ^ (l16 & 7)) * 8;           // kk=0 swizzled slot
    int ck1 = ck0 ^ 32;                         // kk=1

    floatx4 acc[4][4];
    #pragma unroll
    for (int mm = 0; mm < 4; ++mm)
        #pragma unroll
        for (int nn = 0; nn < 4; ++nn) acc[mm][nn] = (floatx4){0.f, 0.f, 0.f, 0.f};

    // prologue: tiles 0 and 1 in flight
    STAGE(&As[0][0], &Bs[0][0], 0);
    STAGE(&As[1][0], &Bs[1][0], 64);

    #pragma unroll 2
    for (int t = 0; t < 14; ++t) { TILE(t, false, true); }
    TILE(14, false, false);
    TILE(15, true, false);    // last tile: full drain

    // epilogue. C/D layout: col = l16 (n), row = quad*4 + j (m)
    if (mode == 1) {
        float* Of = (float*)O0;
        #pragma unroll
        for (int mf = 0; mf < 4; ++mf)
            #pragma unroll
            for (int j = 0; j < 4; ++j) {
                int m = m0 + wm * 64 + mf * 16 + quad * 4 + j;
                #pragma unroll
                for (int nf = 0; nf < 4; ++nf) {
                    int n = n0 + wn * 64 + nf * 16 + l16;
                    Of[(size_t)m * CEMB + n] = acc[mf][nf][j];
                }
            }
    } else {
        int which = n0 >> 10;   // 256-wide tile inside a 1024-aligned third
        unsigned short* out = (unsigned short*)(which == 0 ? O0 : which == 1 ? O1 : O2);
        if (which < 2) {
            // Q or K -> (B,H,L,hd) bf16
            #pragma unroll
            for (int mf = 0; mf < 4; ++mf)
                #pragma unroll
                for (int j = 0; j < 4; ++j) {
                    int m = m0 + wm * 64 + mf * 16 + quad * 4 + j;
                    int bb = m >> 11, ll = m & (SEQ - 1);
                    #pragma unroll
                    for (int nf = 0; nf < 4; ++nf) {
                        int n = (n0 & (CEMB - 1)) + wn * 64 + nf * 16 + l16;
                        int h = n >> 6, d = n & (HD - 1);
                        out[(size_t)((bb * NHEAD + h) * SEQ + ll) * HD + d] =
                            f2bf(acc[mf][nf][j]);
                    }
                }
        } else {
            // V -> transposed (B,H,hd,L); 4 consecutive m per fragment -> ushort4
            #pragma unroll
            for (int mf = 0; mf < 4; ++mf) {
                int m = m0 + wm * 64 + mf * 16 + quad * 4;
                int bb = m >> 11, ll = m & (SEQ - 1);
                #pragma unroll
                for (int nf = 0; nf < 4; ++nf) {
                    int n = (n0 & (CEMB - 1)) + wn * 64 + nf * 16 + l16;
                    int h = n >> 6, d = n & (HD - 1);
                    ushort4 o4;
                    o4.x = f2bf(acc[mf][nf][0]); o4.y = f2bf(acc[mf][nf][1]);
                    o4.z = f2bf(acc[mf][nf][2]); o4.w = f2bf(acc[mf][nf][3]);
                    *(ushort4*)&out[(size_t)((bb * NHEAD + h) * HD + d) * SEQ + ll] = o4;
                }
            }
        }
    }
}

// Flash attention. Grid: 1024 single-q-tile blocks; LDS 48KB -> 3 blocks/CU.
// NEW vs round 4:
//  (1) K/V double-buffered, ONE barrier per key-tile: iter t = {copy mask regs;
//      prefetch regs t+1; BARRIER; compute from buf[t&1]; ds-store t+1 into
//      buf[t&1 ^1]}. Cross-wave hazards: stores(t) drained by the lgkm in
//      BARRIER; compute(t-1) reads of buf[(t+1)&1] finished before BARRIER.
//  (2) staging-store bank-conflict fix: dest chunk = p0^(r0&7) (was p0 -> all
//      8 rows of a wave hit bank p0*4, 8-way conflict = the 2.16M counter).
//      Source is now LINEAR p0; XOR involution => LDS layout unchanged, read
//      path untouched.
// S computed TRANSPOSED (S^T = K Q^T); fixed-max softmax via raw v_exp.
__launch_bounds__(256, 2)
__global__ void attn_mfma(const unsigned short* __restrict__ Qb,
                          const unsigned short* __restrict__ Kb,
                          const unsigned short* __restrict__ Vtg,
                          const int* __restrict__ amask,
                          unsigned short* __restrict__ Yb) {
    __shared__ unsigned short Ks[2][64 * 64];   // [buf][key][d], chunk pos = c ^ (key&7)
    __shared__ unsigned short Vs[2][64 * 64];   // [buf][d][key], chunk pos = c ^ (d&7)
    __shared__ unsigned short Ps[128 * 64];     // [q][key], wave-private slabs

    int tid = threadIdx.x;
    int wave = tid >> 6;
    int lane = tid & 63;
    int l16 = lane & 15;
    int quad = lane >> 4;
    int l7 = l16 & 7;

    int n = blockIdx.x;
    int rr = n >> 8;                // round 0..3
    int i = n & 255;
    int base = i & 15;
    int bh = (i >> 4) + (rr << 4);  // 0..63
    int qt = (rr == 0) ? base
           : (rr == 1) ? 15 - base
           : (rr == 2) ? (base ^ 8)
                       : 15 - (base ^ 8);

    int bidx = bh >> 4;
    int h = bh & (NHEAD - 1);
    size_t hbase = (size_t)bh * SEQ * HD;

    // staging addresses: dest chunk XOR-swizzled, source LINEAR
    int r0 = tid >> 3, p0 = tid & 7;
    int cl = p0 ^ (r0 & 7);
    int kDoff = r0 * 64 + cl * 8;               // + buf*4096 (elements)
    const unsigned short* kSrc0 = Kb + hbase + (size_t)r0 * HD + p0 * 8;
    const unsigned short* kSrc1 = kSrc0 + (size_t)32 * HD;
    const unsigned short* vSrc0 = Vtg + hbase + (size_t)r0 * SEQ + p0 * 8;
    const unsigned short* vSrc1 = vSrc0 + (size_t)32 * SEQ;
    const int* mSrc = amask + bidx * SEQ + quad * 4;   // + jt*64 + t*16

    int q0 = qt * 128;
    int nkt = 2 * qt + 2;

    // Q fragments in registers
    short8 qf[2][2];
    #pragma unroll
    for (int qsub = 0; qsub < 2; ++qsub)
        #pragma unroll
        for (int kk = 0; kk < 2; ++kk)
            qf[qsub][kk] = *(const short8*)(Qb + hbase +
                (size_t)(q0 + wave * 32 + qsub * 16 + l16) * HD + kk * 32 + quad * 8);

    // prefetch tile 0 regs
    short8 kr0 = *(const short8*)(kSrc0);
    short8 kr1 = *(const short8*)(kSrc1);
    short8 vr0 = *(const short8*)(vSrc0);
    short8 vr1 = *(const short8*)(vSrc1);
    int4 cmi[4];
    #pragma unroll
    for (int t = 0; t < 4; ++t) cmi[t] = *(const int4*)(mSrc + t * 16);

    // store tile 0 into buf 0
    *(short8*)(&Ks[0][0] + kDoff) = kr0;
    *(short8*)(&Ks[0][0] + kDoff + 32 * 64) = kr1;
    *(short8*)(&Vs[0][0] + kDoff) = vr0;
    *(short8*)(&Vs[0][0] + kDoff + 32 * 64) = vr1;

    floatx4 o[2][4];
    #pragma unroll
    for (int qsub = 0; qsub < 2; ++qsub)
        #pragma unroll
        for (int t = 0; t < 4; ++t) o[qsub][t] = (floatx4){0.f, 0.f, 0.f, 0.f};
    float ls[2] = {0.f, 0.f};

    int qw = q0 + wave * 32;   // wave's first q row

    for (int jt = 0; jt < nkt; ++jt) {
        int cur = jt & 1;
        const unsigned short* KsC = &Ks[0][0] + cur * 4096;
        const unsigned short* VsC = &Vs[0][0] + cur * 4096;

        int4 cm[4];
        #pragma unroll
        for (int t = 0; t < 4; ++t) cm[t] = cmi[t];
        if (jt + 1 < nkt) {   // prefetch regs for next tile (hidden under compute)
            size_t ko = (size_t)(jt + 1) * 64;
            kr0 = *(const short8*)(kSrc0 + ko * HD);
            kr1 = *(const short8*)(kSrc1 + ko * HD);
            vr0 = *(const short8*)(vSrc0 + ko);
            vr1 = *(const short8*)(vSrc1 + ko);
            #pragma unroll
            for (int t = 0; t < 4; ++t) cmi[t] = *(const int4*)(mSrc + (jt + 1) * 64 + t * 16);
        }

        BARRIER();   // stores(jt) visible everywhere; all waves past compute(jt-1)

        if (jt * 64 <= qw + 31) {   // wave-uniform: tile not fully above diagonal
            // S^T = K Q^T : A-frag from K rows (keys), B-frag = Q regs
            floatx4 sc[2][4];
            #pragma unroll
            for (int qsub = 0; qsub < 2; ++qsub)
                #pragma unroll
                for (int t = 0; t < 4; ++t) sc[qsub][t] = (floatx4){0.f, 0.f, 0.f, 0.f};
            #pragma unroll
            for (int kk = 0; kk < 2; ++kk)
                #pragma unroll
                for (int t = 0; t < 4; ++t) {
                    short8 aK = *(const short8*)(KsC + (t * 16 + l16) * 64 +
                                                 ((kk * 4 + quad) ^ l7) * 8);
                    #pragma unroll
                    for (int qsub = 0; qsub < 2; ++qsub)
                        sc[qsub][t] = __builtin_amdgcn_mfma_f32_16x16x32_bf16(
                            aK, qf[qsub][kk], sc[qsub][t], 0, 0, 0);
                }

            bool needc = (jt * 64 + 63 > qw);   // diagonal-touching tile for this wave

            // softmax: lane holds q = l16 (per qsub), keys = jt*64 + t*16 + quad*4 + j
            #pragma unroll
            for (int qsub = 0; qsub < 2; ++qsub) {
                int qi = q0 + wave * 32 + qsub * 16 + l16;
                #pragma unroll
                for (int t = 0; t < 4; ++t) {
                    int kb = jt * 64 + t * 16 + quad * 4;
                    float p[4];
                    #pragma unroll
                    for (int j = 0; j < 4; ++j) {
                        float sv = sc[qsub][t][j];
                        if (needc) sv = (kb + j <= qi) ? sv : -1e30f;
                        sv = cm[t][j] ? sv : -1e30f;           // key-padding mask
                        p[j] = __builtin_amdgcn_exp2f(sv);     // raw v_exp_f32
                        ls[qsub] += p[j];
                    }
                    // packed b64 store of 4 consecutive keys (truncating bf16)
                    int row = wave * 32 + qsub * 16 + l16;
                    int pos = (t * 2 + (quad >> 1)) ^ l7;
                    uint2 pk;
                    pk.x = packbf_trunc(p[0], p[1]);
                    pk.y = packbf_trunc(p[2], p[3]);
                    *(uint2*)(Ps + row * 64 + pos * 8 + (quad & 1) * 4) = pk;
                }
            }

            // O += P V  (Ps wave-private slabs)
            #pragma unroll
            for (int kk = 0; kk < 2; ++kk) {
                short8 pa[2];
                #pragma unroll
                for (int qsub = 0; qsub < 2; ++qsub)
                    pa[qsub] = *(const short8*)(Ps + (wave * 32 + qsub * 16 + l16) * 64 +
                                                ((kk * 4 + quad) ^ l7) * 8);
                #pragma unroll
                for (int t = 0; t < 4; ++t) {
                    short8 vb = *(const short8*)(VsC + (t * 16 + l16) * 64 +
                                                 ((kk * 4 + quad) ^ l7) * 8);
                    #pragma unroll
                    for (int qsub = 0; qsub < 2; ++qsub)
                        o[qsub][t] = __builtin_amdgcn_mfma_f32_16x16x32_bf16(
                            pa[qsub], vb, o[qsub][t], 0, 0, 0);
                }
            }
        }

        if (jt + 1 < nkt) {   // ds-store next tile into the other buffer
            unsigned short* kD = &Ks[0][0] + (cur ^ 1) * 4096 + kDoff;
            unsigned short* vD = &Vs[0][0] + (cur ^ 1) * 4096 + kDoff;
            *(short8*)kD = kr0;
            *(short8*)(kD + 32 * 64) = kr1;
            *(short8*)vD = vr0;
            *(short8*)(vD + 32 * 64) = vr1;
        }
    }

    // ls: sum over quads (lanes 16 apart hold same q = l16)
    #pragma unroll
    for (int qsub = 0; qsub < 2; ++qsub) {
        ls[qsub] += __shfl_xor(ls[qsub], 16, 64);
        ls[qsub] += __shfl_xor(ls[qsub], 32, 64);
    }

    // epilogue: o rows are q = quad*4+j; fetch l from lane (quad*4+j)
    #pragma unroll
    for (int qsub = 0; qsub < 2; ++qsub)
        #pragma unroll
        for (int j = 0; j < 4; ++j) {
            float lq = __shfl(ls[qsub], quad * 4 + j, 64);
            float inv = 1.0f / lq;
            size_t row = (size_t)bidx * SEQ + q0 + wave * 32 + qsub * 16 + quad * 4 + j;
            #pragma unroll
            for (int t = 0; t < 4; ++t)
                Yb[row * CEMB + h * HD + t * 16 + l16] = f2bf(o[qsub][t][j] * inv);
        }
}

extern "C" void kernel_launch(void* const* d_in, const int* in_sizes, int n_in,
                              void* d_out, int out_size, void* d_ws, size_t ws_size,
                              hipStream_t stream) {
    const float* x  = (const float*)d_in[0];
    const float* Wq = (const float*)d_in[1];
    const float* Wk = (const float*)d_in[2];
    const float* Wv = (const float*)d_in[3];
    const float* Wp = (const float*)d_in[4];
    const int* amask = (const int*)d_in[5];

    char* ws = (char*)d_ws;
    unsigned short* xb  = (unsigned short*)(ws + 0);
    unsigned short* Wqb = (unsigned short*)(ws + (16u << 20));  // Wq|Wk|Wv contiguous = 3072x1024
    unsigned short* Wkb = (unsigned short*)(ws + (18u << 20));
    unsigned short* Wvb = (unsigned short*)(ws + (20u << 20));
    unsigned short* Wpb = (unsigned short*)(ws + (22u << 20));
    unsigned short* Qb  = (unsigned short*)(ws + (24u << 20));  // (B,H,L,hd)
    unsigned short* Kb  = (unsigned short*)(ws + (40u << 20));  // (B,H,L,hd)
    unsigned short* Vtg = (unsigned short*)(ws + (56u << 20));  // (B,H,hd,L)
    unsigned short* Yb  = (unsigned short*)(ws + (72u << 20));  // (B,L,C)

    const int NX4 = (BATCH * SEQ * CEMB) / 4;
    const int NW4 = (CEMB * CEMB) / 4;
    cast_x<<<dim3(NX4 / 256), 256, 0, stream>>>(x, xb, NX4);
    cast_w<<<dim3(NW4 / 256, 4), 256, 0, stream>>>(Wq, Wk, Wv, Wp, Wqb, Wkb, Wvb, Wpb);

    // fused QKV: 8192 x 3072 x 1024 -> 64m x 12n = 768 blocks = 3 exact rounds
    gemm_128<<<dim3(768), 512, 0, stream>>>(
        xb, Wqb, (void*)Qb, (void*)Kb, (void*)Vtg, 0, 12);

    attn_mfma<<<dim3(1024), 256, 0, stream>>>(Qb, Kb, Vtg, amask, Yb);

    // projection: 8192 x 1024 x 1024 -> 64m x 4n = 256 blocks = one full round
    gemm_128<<<dim3(256), 512, 0, stream>>>(
        Yb, Wpb, d_out, nullptr, nullptr, 1, 4);
}

// Round 6
// 247.335 us; speedup vs baseline: 1.1962x; 1.1962x over previous
//
#include <hip/hip_runtime.h>

typedef __attribute__((ext_vector_type(8))) short short8;
typedef __attribute__((ext_vector_type(4))) float floatx4;

#define CEMB 1024
#define NHEAD 16
#define HD 64
#define BATCH 4
#define SEQ 2048

// raw barrier: LDS-visibility only, no vmcnt drain (keeps register prefetch in flight)
#define BARRIER() asm volatile("s_waitcnt lgkmcnt(0)\n\ts_barrier" ::: "memory")

__device__ __forceinline__ unsigned short f2bf(float f) {
    union { float f; unsigned int i; } x; x.f = f;
    unsigned int r = x.i + 0x7FFFu + ((x.i >> 16) & 1u);
    return (unsigned short)(r >> 16);
}
// truncating bf16 pack of two floats (low = a, high = b)
__device__ __forceinline__ unsigned int packbf_trunc(float a, float b) {
    union { float f; unsigned int u; } x, y; x.f = a; y.f = b;
    return (x.u >> 16) | (y.u & 0xFFFF0000u);
}

#define GLD16(gp, lp) \
    __builtin_amdgcn_global_load_lds((const __attribute__((address_space(1))) void*)(gp), \
                                     (__attribute__((address_space(3))) void*)(lp), 16, 0, 0)

__global__ void cast_x(const float* __restrict__ src, unsigned short* __restrict__ dst, int n4) {
    int i = blockIdx.x * blockDim.x + threadIdx.x;
    if (i < n4) {
        float4 v = ((const float4*)src)[i];
        ushort4 o;
        o.x = f2bf(v.x); o.y = f2bf(v.y); o.z = f2bf(v.z); o.w = f2bf(v.w);
        ((ushort4*)dst)[i] = o;
    }
}

__global__ void cast_w(const float* __restrict__ w0, const float* __restrict__ w1,
                       const float* __restrict__ w2, const float* __restrict__ w3,
                       unsigned short* __restrict__ o0, unsigned short* __restrict__ o1,
                       unsigned short* __restrict__ o2, unsigned short* __restrict__ o3) {
    int which = blockIdx.y;
    const float* src = which == 0 ? w0 : which == 1 ? w1 : which == 2 ? w2 : w3;
    unsigned short* dst = which == 0 ? o0 : which == 1 ? o1 : which == 2 ? o2 : o3;
    // fold 1/sqrt(hd) AND log2(e) into Wq so attention can use raw v_exp (exp2)
    float scale = (which == 0) ? 0.125f * 1.44269504088896f : 1.0f;
    int i = blockIdx.x * blockDim.x + threadIdx.x;
    float4 v = ((const float4*)src)[i];
    ushort4 o;
    o.x = f2bf(v.x * scale); o.y = f2bf(v.y * scale);
    o.z = f2bf(v.z * scale); o.w = f2bf(v.w * scale);
    ((ushort4*)dst)[i] = o;
}

// ============================================================================
// GEMM, 128x128 tile, BK=64, 4 waves (2M x 2N, wave tile 64x64), double-
// buffered LDS = 64 KiB -> 2 blocks/CU co-resident (the R4 96KB version ran
// 1 block/CU: every barrier stalled the whole CU with nothing to overlap).
// R4's counted-vmcnt pipeline kept: 2 barriers/K-tile, stage(t+2) bursts
// after the lgkm-drain barrier, vmcnt(8) never drains to 0 mid-loop.
// LDS XOR-swizzle (T2), setprio (T5), XCD bijective swizzle + 8m x 4n
// supertile walk (L2 residency: A 2MB + B 1MB per chunk).
// ============================================================================

#define MFMA __builtin_amdgcn_mfma_f32_16x16x32_bf16

// one phase: 6 ds_read_b128 + 16 MFMA (cols 0,1)
#define PH(Ab, Bb) do {                                                         \
    short8 af[4][2], bfr[2][2];                                                 \
    _Pragma("unroll")                                                           \
    for (int mm = 0; mm < 4; ++mm) {                                            \
        af[mm][0] = *(const short8*)((Ab) + aOffR + mm*1024 + ck0);             \
        af[mm][1] = *(const short8*)((Ab) + aOffR + mm*1024 + ck1);             \
    }                                                                           \
    _Pragma("unroll")                                                           \
    for (int nn = 0; nn < 2; ++nn) {                                            \
        bfr[nn][0] = *(const short8*)((Bb) + bOffR + nn*1024 + ck0);            \
        bfr[nn][1] = *(const short8*)((Bb) + bOffR + nn*1024 + ck1);            \
    }                                                                           \
    __builtin_amdgcn_s_setprio(1);                                              \
    _Pragma("unroll")                                                           \
    for (int mm = 0; mm < 4; ++mm)                                              \
        _Pragma("unroll")                                                       \
        for (int nn = 0; nn < 2; ++nn) {                                        \
            acc[mm][nn] = MFMA(af[mm][0], bfr[nn][0], acc[mm][nn], 0,0,0);      \
            acc[mm][nn] = MFMA(af[mm][1], bfr[nn][1], acc[mm][nn], 0,0,0);      \
        }                                                                       \
    __builtin_amdgcn_s_setprio(0);                                              \
    __builtin_amdgcn_sched_barrier(0);                                          \
} while (0)

// stage one K-tile: A 128x64 (4 loads) + B 128x64 (4 loads); wave covers 32 rows
#define STAGE(Ab, Bb, k0) do {                                                  \
    GLD16(aS + (k0),             (Ab) + aLS);                                   \
    GLD16(aS + (k0) +  8 * CEMB, (Ab) + aLS + 512);                             \
    GLD16(aS + (k0) + 16 * CEMB, (Ab) + aLS + 1024);                            \
    GLD16(aS + (k0) + 24 * CEMB, (Ab) + aLS + 1536);                            \
    GLD16(bS + (k0),             (Bb) + aLS);                                   \
    GLD16(bS + (k0) +  8 * CEMB, (Bb) + aLS + 512);                             \
    GLD16(bS + (k0) + 16 * CEMB, (Bb) + aLS + 1024);                            \
    GLD16(bS + (k0) + 24 * CEMB, (Bb) + aLS + 1536);                            \
} while (0)

// last phase (cols 2,3): reads, lgkm drain, barrier (buffer release),
// stage t+2 into the SAME buffer, then MFMAs on the already-fetched registers.
#define PH4(Ab, Bb, t, do_stage) do {                                           \
    short8 af[4][2], bfr[2][2];                                                 \
    _Pragma("unroll")                                                           \
    for (int mm = 0; mm < 4; ++mm) {                                            \
        af[mm][0] = *(const short8*)((Ab) + aOffR + mm*1024 + ck0);             \
        af[mm][1] = *(const short8*)((Ab) + aOffR + mm*1024 + ck1);             \
    }                                                                           \
    _Pragma("unroll")                                                           \
    for (int nn = 0; nn < 2; ++nn) {                                            \
        bfr[nn][0] = *(const short8*)((Bb) + bOffR + (2+nn)*1024 + ck0);        \
        bfr[nn][1] = *(const short8*)((Bb) + bOffR + (2+nn)*1024 + ck1);        \
    }                                                                           \
    asm volatile("s_waitcnt lgkmcnt(0)\n\ts_barrier" ::: "memory");             \
    __builtin_amdgcn_sched_barrier(0);                                          \
    if (do_stage) STAGE(Ab, Bb, ((t) + 2) * 64);                                \
    __builtin_amdgcn_s_setprio(1);                                              \
    _Pragma("unroll")                                                           \
    for (int mm = 0; mm < 4; ++mm)                                              \
        _Pragma("unroll")                                                       \
        for (int nn = 0; nn < 2; ++nn) {                                        \
            acc[mm][2+nn] = MFMA(af[mm][0], bfr[nn][0], acc[mm][2+nn], 0,0,0);  \
            acc[mm][2+nn] = MFMA(af[mm][1], bfr[nn][1], acc[mm][2+nn], 0,0,0);  \
        }                                                                       \
    __builtin_amdgcn_s_setprio(0);                                              \
    __builtin_amdgcn_sched_barrier(0);                                          \
} while (0)

// tile top: wait tile t resident (stage(t+1)'s 8 loads may stay in flight)
#define TILE(t, drain, do_stage) do {                                           \
    unsigned short* Ab = &As[(t) & 1][0];                                       \
    unsigned short* Bb = &Bs[(t) & 1][0];                                       \
    if (drain) { asm volatile("s_waitcnt vmcnt(0)" ::: "memory"); }             \
    else       { asm volatile("s_waitcnt vmcnt(8)" ::: "memory"); }             \
    asm volatile("s_barrier" ::: "memory");                                     \
    PH(Ab, Bb);                                                                 \
    PH4(Ab, Bb, t, do_stage);                                                   \
} while (0)

__launch_bounds__(256, 2)
__global__ void gemm_128(const unsigned short* __restrict__ A,
                         const unsigned short* __restrict__ W,
                         void* __restrict__ O0, void* __restrict__ O1,
                         void* __restrict__ O2, int mode, int ntn) {
    __shared__ unsigned short As[2][8192];    // 2 x 128 rows x 64 cols bf16
    __shared__ unsigned short Bs[2][8192];    // 2 x 128 rows x 64 cols bf16

    // XCD-aware bijective swizzle (nwg % 8 == 0) + 8m x 4n supertile walk:
    // each 32-wg chunk covers 8 m-tiles x 4 n-tiles (A 2MB + B 1MB in L2).
    int nwg = gridDim.x;
    int bid = blockIdx.x;
    int wg = (bid & 7) * (nwg >> 3) + (bid >> 3);
    int cpr = ntn >> 2;                 // n-chunks per 8-row m-band
    int c = wg >> 5, r = wg & 31;
    int cm = c / cpr, cn = c - cm * cpr;
    int mt = cm * 8 + (r >> 2);
    int nt = cn * 4 + (r & 3);
    int m0 = mt * 128, n0 = nt * 128;

    int tid = threadIdx.x;
    int wave = tid >> 6, lane = tid & 63;
    int l16 = lane & 15, quad = lane >> 4;
    int wm = wave >> 1, wn = wave & 1;

    // staging: source col pre-swizzled: LDS slot c of row r holds chunk c^(r&7)
    int srow = lane >> 3;                       // 0..7
    int scol = ((lane & 7) ^ srow) * 8;
    const unsigned short* aS = A + (size_t)(m0 + wave * 32 + srow) * CEMB + scol;
    const unsigned short* bS = W + (size_t)(n0 + wave * 32 + srow) * CEMB + scol;
    int aLS = wave * 2048;                      // wave-uniform LDS slab (32 rows)

    // fragment-read addressing (row&7 == l16&7 for all frag rows)
    int aOffR = (wm * 64 + l16) * 64;
    int bOffR = (wn * 64 + l16) * 64;
    int ck0 = (quad ^ (l16 & 7)) * 8;           // kk=0 swizzled slot
    int ck1 = ck0 ^ 32;                         // kk=1

    floatx4 acc[4][4];
    #pragma unroll
    for (int mm = 0; mm < 4; ++mm)
        #pragma unroll
        for (int nn = 0; nn < 4; ++nn) acc[mm][nn] = (floatx4){0.f, 0.f, 0.f, 0.f};

    // prologue: tiles 0 and 1 in flight (16 loads)
    STAGE(&As[0][0], &Bs[0][0], 0);
    STAGE(&As[1][0], &Bs[1][0], 64);

    #pragma unroll 2
    for (int t = 0; t < 14; ++t) { TILE(t, false, true); }
    TILE(14, false, false);
    TILE(15, true, false);    // last tile: full drain

    // epilogue. C/D layout: col = l16 (n), row = quad*4 + j (m)
    if (mode == 1) {
        float* Of = (float*)O0;
        #pragma unroll
        for (int mf = 0; mf < 4; ++mf)
            #pragma unroll
            for (int j = 0; j < 4; ++j) {
                int m = m0 + wm * 64 + mf * 16 + quad * 4 + j;
                #pragma unroll
                for (int nf = 0; nf < 4; ++nf) {
                    int n = n0 + wn * 64 + nf * 16 + l16;
                    Of[(size_t)m * CEMB + n] = acc[mf][nf][j];
                }
            }
    } else {
        int which = n0 >> 10;   // 128-wide tile inside a 1024-aligned third
        unsigned short* out = (unsigned short*)(which == 0 ? O0 : which == 1 ? O1 : O2);
        if (which < 2) {
            // Q or K -> (B,H,L,hd) bf16
            #pragma unroll
            for (int mf = 0; mf < 4; ++mf)
                #pragma unroll
                for (int j = 0; j < 4; ++j) {
                    int m = m0 + wm * 64 + mf * 16 + quad * 4 + j;
                    int bb = m >> 11, ll = m & (SEQ - 1);
                    #pragma unroll
                    for (int nf = 0; nf < 4; ++nf) {
                        int n = (n0 & (CEMB - 1)) + wn * 64 + nf * 16 + l16;
                        int h = n >> 6, d = n & (HD - 1);
                        out[(size_t)((bb * NHEAD + h) * SEQ + ll) * HD + d] =
                            f2bf(acc[mf][nf][j]);
                    }
                }
        } else {
            // V -> transposed (B,H,hd,L); 4 consecutive m per fragment -> ushort4
            #pragma unroll
            for (int mf = 0; mf < 4; ++mf) {
                int m = m0 + wm * 64 + mf * 16 + quad * 4;
                int bb = m >> 11, ll = m & (SEQ - 1);
                #pragma unroll
                for (int nf = 0; nf < 4; ++nf) {
                    int n = (n0 & (CEMB - 1)) + wn * 64 + nf * 16 + l16;
                    int h = n >> 6, d = n & (HD - 1);
                    ushort4 o4;
                    o4.x = f2bf(acc[mf][nf][0]); o4.y = f2bf(acc[mf][nf][1]);
                    o4.z = f2bf(acc[mf][nf][2]); o4.w = f2bf(acc[mf][nf][3]);
                    *(ushort4*)&out[(size_t)((bb * NHEAD + h) * HD + d) * SEQ + ll] = o4;
                }
            }
        }
    }
}

// Flash attention (round-4 version, best measured: 80 us). Grid: 1024
// single-q-tile blocks; LDS 32KB. Per-CU balance: rounds get qt
// {a, 15-a, a^8, 15-(a^8)} -> uniform 68 key-tile iterations per slot-group.
// S computed TRANSPOSED (S^T = K Q^T); fixed-max softmax via raw v_exp.
__launch_bounds__(256, 2)
__global__ void attn_mfma(const unsigned short* __restrict__ Qb,
                          const unsigned short* __restrict__ Kb,
                          const unsigned short* __restrict__ Vtg,
                          const int* __restrict__ amask,
                          unsigned short* __restrict__ Yb) {
    __shared__ unsigned short Ks[64 * 64];   // [key][d], chunk pos = c ^ (key&7)
    __shared__ unsigned short Vs[64 * 64];   // [d][key], chunk pos = c ^ (d&7)
    __shared__ unsigned short Ps[128 * 64];  // [q][key], wave-private slabs

    int tid = threadIdx.x;
    int wave = tid >> 6;
    int lane = tid & 63;
    int l16 = lane & 15;
    int quad = lane >> 4;
    int l7 = l16 & 7;

    int n = blockIdx.x;
    int rr = n >> 8;                // round 0..3
    int i = n & 255;
    int base = i & 15;
    int bh = (i >> 4) + (rr << 4);  // 0..63
    int qt = (rr == 0) ? base
           : (rr == 1) ? 15 - base
           : (rr == 2) ? (base ^ 8)
                       : 15 - (base ^ 8);

    int bidx = bh >> 4;
    int h = bh & (NHEAD - 1);
    size_t hbase = (size_t)bh * SEQ * HD;

    // staging addresses (tile-invariant parts)
    int r0 = tid >> 3, p0 = tid & 7;
    int cl = p0 ^ (r0 & 7);
    unsigned short* kDst0 = Ks + r0 * 64 + p0 * 8;
    unsigned short* kDst1 = kDst0 + 32 * 64;
    unsigned short* vDst0 = Vs + r0 * 64 + p0 * 8;
    unsigned short* vDst1 = vDst0 + 32 * 64;
    const unsigned short* kSrc0 = Kb + hbase + (size_t)r0 * HD + cl * 8;
    const unsigned short* kSrc1 = kSrc0 + (size_t)32 * HD;
    const unsigned short* vSrc0 = Vtg + hbase + (size_t)r0 * SEQ + cl * 8;
    const unsigned short* vSrc1 = vSrc0 + (size_t)32 * SEQ;
    const int* mSrc = amask + bidx * SEQ + quad * 4;   // + jt*64 + t*16

    int q0 = qt * 128;
    int nkt = 2 * qt + 2;

    // Q fragments in registers
    short8 qf[2][2];
    #pragma unroll
    for (int qsub = 0; qsub < 2; ++qsub)
        #pragma unroll
        for (int kk = 0; kk < 2; ++kk)
            qf[qsub][kk] = *(const short8*)(Qb + hbase +
                (size_t)(q0 + wave * 32 + qsub * 16 + l16) * HD + kk * 32 + quad * 8);

    // prefetch tile 0
    short8 kr0 = *(const short8*)(kSrc0);
    short8 kr1 = *(const short8*)(kSrc1);
    short8 vr0 = *(const short8*)(vSrc0);
    short8 vr1 = *(const short8*)(vSrc1);
    int4 cmi[4];
    #pragma unroll
    for (int t = 0; t < 4; ++t) cmi[t] = *(const int4*)(mSrc + t * 16);

    floatx4 o[2][4];
    #pragma unroll
    for (int qsub = 0; qsub < 2; ++qsub)
        #pragma unroll
        for (int t = 0; t < 4; ++t) o[qsub][t] = (floatx4){0.f, 0.f, 0.f, 0.f};
    float ls[2] = {0.f, 0.f};

    int qw = q0 + wave * 32;   // wave's first q row

    for (int jt = 0; jt < nkt; ++jt) {
        BARRIER();   // prior iter's LDS reads done
        *(short8*)kDst0 = kr0;
        *(short8*)kDst1 = kr1;
        *(short8*)vDst0 = vr0;
        *(short8*)vDst1 = vr1;
        int4 cm[4];
        #pragma unroll
        for (int t = 0; t < 4; ++t) cm[t] = cmi[t];
        if (jt + 1 < nkt) {   // prefetch next tile
            size_t ko = (size_t)(jt + 1) * 64;
            kr0 = *(const short8*)(kSrc0 + ko * HD);
            kr1 = *(const short8*)(kSrc1 + ko * HD);
            vr0 = *(const short8*)(vSrc0 + ko);
            vr1 = *(const short8*)(vSrc1 + ko);
            #pragma unroll
            for (int t = 0; t < 4; ++t) cmi[t] = *(const int4*)(mSrc + (jt + 1) * 64 + t * 16);
        }
        BARRIER();   // staging visible

        if (jt * 64 <= qw + 31) {   // wave-uniform: tile not fully above diagonal
            // S^T = K Q^T : A-frag from K rows (keys), B-frag = Q regs
            floatx4 sc[2][4];
            #pragma unroll
            for (int qsub = 0; qsub < 2; ++qsub)
                #pragma unroll
                for (int t = 0; t < 4; ++t) sc[qsub][t] = (floatx4){0.f, 0.f, 0.f, 0.f};
            #pragma unroll
            for (int kk = 0; kk < 2; ++kk)
                #pragma unroll
                for (int t = 0; t < 4; ++t) {
                    short8 aK = *(const short8*)(Ks + (t * 16 + l16) * 64 +
                                                 ((kk * 4 + quad) ^ l7) * 8);
                    #pragma unroll
                    for (int qsub = 0; qsub < 2; ++qsub)
                        sc[qsub][t] = __builtin_amdgcn_mfma_f32_16x16x32_bf16(
                            aK, qf[qsub][kk], sc[qsub][t], 0, 0, 0);
                }

            bool needc = (jt * 64 + 63 > qw);   // diagonal-touching tile for this wave

            // softmax: lane holds q = l16 (per qsub), keys = jt*64 + t*16 + quad*4 + j
            #pragma unroll
            for (int qsub = 0; qsub < 2; ++qsub) {
                int qi = q0 + wave * 32 + qsub * 16 + l16;
                #pragma unroll
                for (int t = 0; t < 4; ++t) {
                    int kb = jt * 64 + t * 16 + quad * 4;
                    float p[4];
                    #pragma unroll
                    for (int j = 0; j < 4; ++j) {
                        float sv = sc[qsub][t][j];
                        if (needc) sv = (kb + j <= qi) ? sv : -1e30f;
                        sv = cm[t][j] ? sv : -1e30f;           // key-padding mask
                        p[j] = __builtin_amdgcn_exp2f(sv);     // raw v_exp_f32
                        ls[qsub] += p[j];
                    }
                    // packed b64 store of 4 consecutive keys (truncating bf16)
                    int row = wave * 32 + qsub * 16 + l16;
                    int pos = (t * 2 + (quad >> 1)) ^ l7;
                    uint2 pk;
                    pk.x = packbf_trunc(p[0], p[1]);
                    pk.y = packbf_trunc(p[2], p[3]);
                    *(uint2*)(Ps + row * 64 + pos * 8 + (quad & 1) * 4) = pk;
                }
            }

            // O += P V  (Ps wave-private slabs)
            #pragma unroll
            for (int kk = 0; kk < 2; ++kk) {
                short8 pa[2];
                #pragma unroll
                for (int qsub = 0; qsub < 2; ++qsub)
                    pa[qsub] = *(const short8*)(Ps + (wave * 32 + qsub * 16 + l16) * 64 +
                                                ((kk * 4 + quad) ^ l7) * 8);
                #pragma unroll
                for (int t = 0; t < 4; ++t) {
                    short8 vb = *(const short8*)(Vs + (t * 16 + l16) * 64 +
                                                 ((kk * 4 + quad) ^ l7) * 8);
                    #pragma unroll
                    for (int qsub = 0; qsub < 2; ++qsub)
                        o[qsub][t] = __builtin_amdgcn_mfma_f32_16x16x32_bf16(
                            pa[qsub], vb, o[qsub][t], 0, 0, 0);
                }
            }
        }
    }

    // ls: sum over quads (lanes 16 apart hold same q = l16)
    #pragma unroll
    for (int qsub = 0; qsub < 2; ++qsub) {
        ls[qsub] += __shfl_xor(ls[qsub], 16, 64);
        ls[qsub] += __shfl_xor(ls[qsub], 32, 64);
    }

    // epilogue: o rows are q = quad*4+j; fetch l from lane (quad*4+j)
    #pragma unroll
    for (int qsub = 0; qsub < 2; ++qsub)
        #pragma unroll
        for (int j = 0; j < 4; ++j) {
            float lq = __shfl(ls[qsub], quad * 4 + j, 64);
            float inv = 1.0f / lq;
            size_t row = (size_t)bidx * SEQ + q0 + wave * 32 + qsub * 16 + quad * 4 + j;
            #pragma unroll
            for (int t = 0; t < 4; ++t)
                Yb[row * CEMB + h * HD + t * 16 + l16] = f2bf(o[qsub][t][j] * inv);
        }
}

extern "C" void kernel_launch(void* const* d_in, const int* in_sizes, int n_in,
                              void* d_out, int out_size, void* d_ws, size_t ws_size,
                              hipStream_t stream) {
    const float* x  = (const float*)d_in[0];
    const float* Wq = (const float*)d_in[1];
    const float* Wk = (const float*)d_in[2];
    const float* Wv = (const float*)d_in[3];
    const float* Wp = (const float*)d_in[4];
    const int* amask = (const int*)d_in[5];

    char* ws = (char*)d_ws;
    unsigned short* xb  = (unsigned short*)(ws + 0);
    unsigned short* Wqb = (unsigned short*)(ws + (16u << 20));  // Wq|Wk|Wv contiguous = 3072x1024
    unsigned short* Wkb = (unsigned short*)(ws + (18u << 20));
    unsigned short* Wvb = (unsigned short*)(ws + (20u << 20));
    unsigned short* Wpb = (unsigned short*)(ws + (22u << 20));
    unsigned short* Qb  = (unsigned short*)(ws + (24u << 20));  // (B,H,L,hd)
    unsigned short* Kb  = (unsigned short*)(ws + (40u << 20));  // (B,H,L,hd)
    unsigned short* Vtg = (unsigned short*)(ws + (56u << 20));  // (B,H,hd,L)
    unsigned short* Yb  = (unsigned short*)(ws + (72u << 20));  // (B,L,C)

    const int NX4 = (BATCH * SEQ * CEMB) / 4;
    const int NW4 = (CEMB * CEMB) / 4;
    cast_x<<<dim3(NX4 / 256), 256, 0, stream>>>(x, xb, NX4);
    cast_w<<<dim3(NW4 / 256, 4), 256, 0, stream>>>(Wq, Wk, Wv, Wp, Wqb, Wkb, Wvb, Wpb);

    // fused QKV: 8192 x 3072 x 1024 -> 64m x 24n = 1536 blocks = 3 exact rounds (2/CU)
    gemm_128<<<dim3(1536), 256, 0, stream>>>(
        xb, Wqb, (void*)Qb, (void*)Kb, (void*)Vtg, 0, 24);

    attn_mfma<<<dim3(1024), 256, 0, stream>>>(Qb, Kb, Vtg, amask, Yb);

    // projection: 8192 x 1024 x 1024 -> 64m x 8n = 512 blocks = 1 exact round (2/CU)
    gemm_128<<<dim3(512), 256, 0, stream>>>(
        Yb, Wpb, d_out, nullptr, nullptr, 1, 8);
}